// Round 21
// baseline (235.615 us; speedup 1.0000x reference)
//
#include <hip/hip_runtime.h>
#include <hip/hip_fp16.h>

#define N_NODES 50000
#define N_EDGESx 600000
#define E_TOT   (N_EDGESx + N_NODES)   // 650000
#define NEG_SLOPE 0.2f

typedef _Float16 f16x4 __attribute__((ext_vector_type(4)));
typedef float f32x4 __attribute__((ext_vector_type(4)));

__device__ __forceinline__ float lrelu(float x) { return x > 0.f ? x : NEG_SLOPE * x; }

// ---------------------------------------------------------------- prep weights + edge count (fused)
__global__ __launch_bounds__(256) void prepcnt_k(const float* __restrict__ W1,
                                                 const float* __restrict__ W2,
                                                 _Float16* __restrict__ Bt1,
                                                 _Float16* __restrict__ Bt2,
                                                 const int* __restrict__ ei,
                                                 int* __restrict__ counts) {
    int b = blockIdx.x;
    if (b < 32) {                       // W1: K=128, N=256, no BPERM
        constexpr int K = 128, N = 256;
        int q = b * 256 + threadIdx.x;
        int n = q & (N - 1);
        int k4 = q / N;
        f16x4 v;
#pragma unroll
        for (int i = 0; i < 4; ++i)
            v[i] = (_Float16)W1[(size_t)(k4 * 4 + i) * N + n];
        int idx = n * K + (((k4 >> 1) ^ (n & 15)) << 3) + ((k4 & 1) << 2);
        *(f16x4*)&Bt1[idx] = v;
    } else if (b < 48) {                // W2: K=256, N=64, BPERM (head interleave)
        constexpr int K = 256, N = 64;
        int q = (b - 32) * 256 + threadIdx.x;
        int n = q & (N - 1);
        int k4 = q / N;
        f16x4 v;
#pragma unroll
        for (int i = 0; i < 4; ++i) {
            int kg = k4 * 4 + i;
            int krow = (kg & 3) * 64 + (kg >> 2);
            v[i] = (_Float16)W2[(size_t)krow * N + n];
        }
        int idx = n * K + (((k4 >> 1) ^ (n & 15)) << 3) + ((k4 & 1) << 2);
        *(f16x4*)&Bt2[idx] = v;
    } else {                            // edge count
        int i = (b - 48) * 256 + threadIdx.x;
        if (i >= E_TOT) return;
        int dst = (i < N_EDGESx) ? ei[N_EDGESx + i] : (i - N_EDGESx);
        atomicAdd(&counts[dst], 1);
    }
}

// ---------------------------------------------------------------- CSR build
__global__ __launch_bounds__(1024) void scanA(const int* __restrict__ counts,
                                              int* __restrict__ offs,
                                              int* __restrict__ chunks, int N) {
    __shared__ int sdata[1024];
    int t = threadIdx.x;
    int g = blockIdx.x * 1024 + t;
    int v = (g < N) ? counts[g] : 0;
    sdata[t] = v;
    __syncthreads();
    for (int off = 1; off < 1024; off <<= 1) {
        int x = (t >= off) ? sdata[t - off] : 0;
        __syncthreads();
        sdata[t] += x;
        __syncthreads();
    }
    int incl = sdata[t];
    if (g < N) offs[g] = incl - v;           // exclusive within chunk
    if (t == 1023) chunks[blockIdx.x] = incl;
}

// scanC with scanB folded in: each block redundantly wave-scans the <=64
// chunk totals and picks its own chunk's exclusive prefix (49 ints, trivial).
__global__ __launch_bounds__(1024) void scanC(int* __restrict__ offs,
                                              const int* __restrict__ chunks,
                                              int N, int nch) {
    __shared__ int base_s;
    int t = threadIdx.x;
    if (t < 64) {
        int lane = t;
        int orig = (lane < nch) ? chunks[lane] : 0;
        int v = orig;
#pragma unroll
        for (int off = 1; off < 64; off <<= 1) {
            int u = __shfl_up(v, off);
            if (lane >= off) v += u;
        }
        if (lane == (int)blockIdx.x) base_s = v - orig;   // exclusive prefix
    }
    __syncthreads();
    int g = blockIdx.x * 1024 + t;
    if (g < N) offs[g] += base_s;
}

__global__ __launch_bounds__(256) void scatter_k(const int* __restrict__ ei,
                                                 const int* __restrict__ offs,
                                                 int* __restrict__ cursor,
                                                 int* __restrict__ edge_src) {
    int i = blockIdx.x * 256 + threadIdx.x;
    if (i >= E_TOT) return;
    int src, dst;
    if (i < N_EDGESx) { src = ei[i]; dst = ei[N_EDGESx + i]; }
    else              { src = dst = i - N_EDGESx; }
    int pos = atomicAdd(&cursor[dst], 1);
    edge_src[offs[dst] + pos] = src;
}

// ---------------------------------------------------------------- MFMA GEMM (+fused alpha dots)
template<int K, int N, int CPW, typename AT, int CPERM, int ALPHA>
__global__ __launch_bounds__(256, 2) void gemm_mfma(const AT* __restrict__ A,
                                                    const _Float16* __restrict__ Bt,
                                                    _Float16* __restrict__ C,
                                                    const float* __restrict__ asrc,
                                                    const float* __restrict__ adst,
                                                    float* __restrict__ as_o,
                                                    float* __restrict__ ad_o, int M) {
    __shared__ __align__(16) _Float16 Ah[64 * K];
    __shared__ __align__(16) _Float16 Bh[N * K];
    const int t = threadIdx.x;
    const int row0 = blockIdx.x * 64;

#pragma unroll
    for (int q = t; q < 64 * K / 4; q += 256) {
        int r = q / (K / 4);
        int k4 = q % (K / 4);
        f16x4 v;
        int grow = row0 + r;
        if (grow < M) {
            if constexpr (sizeof(AT) == 4) {
                float4 f = *(const float4*)(A + (size_t)grow * K + k4 * 4);
                v[0] = (_Float16)f.x; v[1] = (_Float16)f.y;
                v[2] = (_Float16)f.z; v[3] = (_Float16)f.w;
            } else {
                v = *(const f16x4*)(A + (size_t)grow * K + k4 * 4);
            }
        } else {
            v[0] = v[1] = v[2] = v[3] = (_Float16)0.f;
        }
        int idx = r * K + (((k4 >> 1) ^ (r & 15)) << 3) + ((k4 & 1) << 2);
        *(f16x4*)&Ah[idx] = v;
    }
    // B staging: pure 16B copy (layout pre-swizzled in prepcnt_k)
#pragma unroll
    for (int q = t; q < N * K / 8; q += 256)
        ((uint4*)Bh)[q] = ((const uint4*)Bt)[q];
    __syncthreads();

    const int w = t >> 6;
    const int l = t & 63;
    const int lr = l & 15;
    const int g = l >> 4;

    f32x4 acc[4][CPW];
#pragma unroll
    for (int mt = 0; mt < 4; ++mt)
#pragma unroll
        for (int nt = 0; nt < CPW; ++nt)
            acc[mt][nt] = (f32x4){0.f, 0.f, 0.f, 0.f};

#pragma unroll
    for (int ks = 0; ks < K / 16; ++ks) {
        int k = ks * 16 + g * 4;
        f16x4 a[4], b[CPW];
#pragma unroll
        for (int mt = 0; mt < 4; ++mt) {
            int r = mt * 16 + lr;
            a[mt] = *(const f16x4*)&Ah[r * K + (((k >> 3) ^ (r & 15)) << 3) + (k & 7)];
        }
#pragma unroll
        for (int nt = 0; nt < CPW; ++nt) {
            int n = (w * CPW + nt) * 16 + lr;
            b[nt] = *(const f16x4*)&Bh[n * K + (((k >> 3) ^ (n & 15)) << 3) + (k & 7)];
        }
#pragma unroll
        for (int mt = 0; mt < 4; ++mt)
#pragma unroll
            for (int nt = 0; nt < CPW; ++nt)
                acc[mt][nt] = __builtin_amdgcn_mfma_f32_16x16x16f16(a[mt], b[nt],
                                                                   acc[mt][nt], 0, 0, 0);
    }

    if constexpr (CPERM) {
        // Ah is dead after the MFMA loop: reuse for a_src/a_dst staging + psums.
        float* A_s  = (float*)Ah;          // [256]
        float* A_d  = A_s + 256;           // [256]
        float* psum = A_d + 256;           // [64][4][8] = 2048 floats
        __syncthreads();
        _Float16* Cs = Bh;
#pragma unroll
        for (int mt = 0; mt < 4; ++mt)
#pragma unroll
            for (int q = 0; q < 4; ++q) {
                int row = mt * 16 + g * 4 + q;
#pragma unroll
                for (int nt = 0; nt < CPW; ++nt) {
                    int gcol = (w * CPW + nt) * 16 + lr;
                    int ocol = ((gcol & 63) << 2) | (gcol >> 6);
                    Cs[row * N + ocol] = (_Float16)acc[mt][nt][q];
                }
            }
        if constexpr (ALPHA == 1) { A_s[t] = asrc[t]; A_d[t] = adst[t]; }
        __syncthreads();
#pragma unroll
        for (int q = t; q < 64 * N / 8; q += 256) {
            int row = q / (N / 8);
            int c8 = q % (N / 8);
            int grow = row0 + row;
            if (grow < M)
                *(float4*)(C + (size_t)grow * N + c8 * 8) =
                    *(const float4*)&Cs[row * N + c8 * 8];
        }
        if constexpr (ALPHA == 1) {
            int row = t & 63, qr = t >> 6;
            float s[4] = {}, d[4] = {};
#pragma unroll
            for (int j = 0; j < 16; ++j) {
                int c = qr * 16 + j;
                union { uint2 u; __half h[4]; } U;
                U.u = *(const uint2*)&Cs[row * 256 + c * 4];
#pragma unroll
                for (int h = 0; h < 4; ++h) {
                    float f = __half2float(U.h[h]);
                    s[h] += f * A_s[h * 64 + c];
                    d[h] += f * A_d[h * 64 + c];
                }
            }
            float* ps = psum + (row * 4 + qr) * 8;
#pragma unroll
            for (int h = 0; h < 4; ++h) { ps[h] = s[h]; ps[4 + h] = d[h]; }
            __syncthreads();
            if (t < 64 && row0 + t < M) {
                float4 S = make_float4(0.f, 0.f, 0.f, 0.f);
                float4 D = make_float4(0.f, 0.f, 0.f, 0.f);
#pragma unroll
                for (int q2 = 0; q2 < 4; ++q2) {
                    float* ps2 = psum + (t * 4 + q2) * 8;
                    S.x += ps2[0]; S.y += ps2[1]; S.z += ps2[2]; S.w += ps2[3];
                    D.x += ps2[4]; D.y += ps2[5]; D.z += ps2[6]; D.w += ps2[7];
                }
                *(float4*)(as_o + (size_t)(row0 + t) * 4) = S;
                *(float4*)(ad_o + (size_t)(row0 + t) * 4) = D;
            }
        }
    } else {
#pragma unroll
        for (int mt = 0; mt < 4; ++mt)
#pragma unroll
            for (int q = 0; q < 4; ++q) {
                int grow = row0 + mt * 16 + g * 4 + q;
                if (grow >= M) continue;
#pragma unroll
                for (int nt = 0; nt < CPW; ++nt) {
                    int gcol = (w * CPW + nt) * 16 + lr;
                    C[(size_t)grow * N + gcol] = (_Float16)acc[mt][nt][q];
                }
            }
        if constexpr (ALPHA == 2) {
            __half* Ch  = (__half*)Ah;            // [64][64] = 8 KB
            float*  A_s = (float*)(Ch + 64 * 64); // [64]
            float*  A_d = A_s + 64;               // [64]
            float*  psum = A_d + 64;              // [64][4][2]
            __syncthreads();
#pragma unroll
            for (int mt = 0; mt < 4; ++mt)
#pragma unroll
                for (int q = 0; q < 4; ++q) {
                    int row = mt * 16 + g * 4 + q;
                    Ch[row * 64 + w * 16 + lr] = __float2half(acc[mt][0][q]);
                }
            if (t < 64) { A_s[t] = asrc[t]; A_d[t] = adst[t]; }
            __syncthreads();
            int row = t & 63, qr = t >> 6;
            float s = 0.f, d = 0.f;
#pragma unroll
            for (int j = 0; j < 16; ++j) {
                int c = qr * 16 + j;
                float f = __half2float(Ch[row * 64 + c]);
                s += f * A_s[c];
                d += f * A_d[c];
            }
            psum[(row * 4 + qr) * 2]     = s;
            psum[(row * 4 + qr) * 2 + 1] = d;
            __syncthreads();
            if (t < 64 && row0 + t < M) {
                float S = 0.f, D = 0.f;
#pragma unroll
                for (int q2 = 0; q2 < 4; ++q2) {
                    S += psum[(t * 4 + q2) * 2];
                    D += psum[(t * 4 + q2) * 2 + 1];
                }
                as_o[row0 + t] = S;
                ad_o[row0 + t] = D;
            }
        }
    }
}

// ---------------------------------------------------------------- stats + weight write (fp16 w)
// Single-gather restructure: lane-per-edge layout (16 rows in flight per
// group, 4x old MLP); as1 float4 cached in regs for <=4 rounds (deg<=64);
// re-gather fallback beyond.  Gathers halve vs the 2-pass version.
__global__ __launch_bounds__(256) void stats1w_k(const int* __restrict__ edge_src,
                                                 const float* __restrict__ as1,
                                                 const float* __restrict__ ad1,
                                                 const int* __restrict__ offs,
                                                 const int* __restrict__ counts,
                                                 __half* __restrict__ w4, int N) {
    int t = threadIdx.x;
    int l16 = t & 15;
    int n = blockIdx.x * 16 + (t >> 4);
    if (n >= N) return;
    int start = offs[n];
    int end = start + counts[n];
    float4 ad = *(const float4*)(ad1 + (size_t)n * 4);
    float4 aa[4];
    float m0 = -1e30f, m1 = -1e30f, m2 = -1e30f, m3 = -1e30f;
    float s0 = 0.f, s1 = 0.f, s2 = 0.f, s3 = 0.f;
    int nr = 0;
    for (int p0 = start; p0 < end; p0 += 16, ++nr) {
        int p = p0 + l16;
        float4 a = make_float4(0.f, 0.f, 0.f, 0.f);
        float e0 = -1e30f, e1 = -1e30f, e2 = -1e30f, e3 = -1e30f;
        float val = 0.f;
        if (p < end) {
            a = *(const float4*)(as1 + (size_t)edge_src[p] * 4);
            e0 = lrelu(a.x + ad.x); e1 = lrelu(a.y + ad.y);
            e2 = lrelu(a.z + ad.z); e3 = lrelu(a.w + ad.w);
            val = 1.f;
        }
        if (nr < 4) aa[nr] = a;
        float nm;
        nm = fmaxf(m0, e0); s0 = s0 * __expf(m0 - nm) + val * __expf(e0 - nm); m0 = nm;
        nm = fmaxf(m1, e1); s1 = s1 * __expf(m1 - nm) + val * __expf(e1 - nm); m1 = nm;
        nm = fmaxf(m2, e2); s2 = s2 * __expf(m2 - nm) + val * __expf(e2 - nm); m2 = nm;
        nm = fmaxf(m3, e3); s3 = s3 * __expf(m3 - nm) + val * __expf(e3 - nm); m3 = nm;
    }
#pragma unroll
    for (int i = 0; i < 4; ++i) {       // butterfly within 16-lane group
        int msk = 1 << i;
        float om, os, nm;
        om = __shfl_xor(m0, msk); os = __shfl_xor(s0, msk);
        nm = fmaxf(m0, om); s0 = s0 * __expf(m0 - nm) + os * __expf(om - nm); m0 = nm;
        om = __shfl_xor(m1, msk); os = __shfl_xor(s1, msk);
        nm = fmaxf(m1, om); s1 = s1 * __expf(m1 - nm) + os * __expf(om - nm); m1 = nm;
        om = __shfl_xor(m2, msk); os = __shfl_xor(s2, msk);
        nm = fmaxf(m2, om); s2 = s2 * __expf(m2 - nm) + os * __expf(om - nm); m2 = nm;
        om = __shfl_xor(m3, msk); os = __shfl_xor(s3, msk);
        nm = fmaxf(m3, om); s3 = s3 * __expf(m3 - nm) + os * __expf(om - nm); m3 = nm;
    }
    float r0 = 1.f / (s0 + 1e-16f), r1 = 1.f / (s1 + 1e-16f);
    float r2 = 1.f / (s2 + 1e-16f), r3 = 1.f / (s3 + 1e-16f);
    nr = 0;
    for (int p0 = start; p0 < end; p0 += 16, ++nr) {
        int p = p0 + l16;
        if (p < end) {
            float4 a = (nr < 4) ? aa[nr]
                                : *(const float4*)(as1 + (size_t)edge_src[p] * 4);
            union { uint2 u; __half h[4]; } W;
            W.h[0] = __float2half(__expf(lrelu(a.x + ad.x) - m0) * r0);
            W.h[1] = __float2half(__expf(lrelu(a.y + ad.y) - m1) * r1);
            W.h[2] = __float2half(__expf(lrelu(a.z + ad.z) - m2) * r2);
            W.h[3] = __float2half(__expf(lrelu(a.w + ad.w) - m3) * r3);
            *(uint2*)(w4 + (size_t)p * 4) = W.u;
        }
    }
}

__global__ __launch_bounds__(256) void stats2w_k(const int* __restrict__ edge_src,
                                                 const float* __restrict__ as2,
                                                 const float* __restrict__ ad2,
                                                 const int* __restrict__ offs,
                                                 const int* __restrict__ counts,
                                                 __half* __restrict__ w2, int N) {
    int t = threadIdx.x;
    int l16 = t & 15;
    int n = blockIdx.x * 16 + (t >> 4);
    if (n >= N) return;
    int start = offs[n];
    int end = start + counts[n];
    float adn = ad2[n];
    float av[4];
    float m = -1e30f, s = 0.f;
    int nr = 0;
    for (int p0 = start; p0 < end; p0 += 16, ++nr) {
        int p = p0 + l16;
        float a = 0.f, e = -1e30f, val = 0.f;
        if (p < end) {
            a = as2[edge_src[p]];
            e = lrelu(a + adn);
            val = 1.f;
        }
        if (nr < 4) av[nr] = a;
        float nm = fmaxf(m, e);
        s = s * __expf(m - nm) + val * __expf(e - nm);
        m = nm;
    }
#pragma unroll
    for (int i = 0; i < 4; ++i) {       // butterfly within 16-lane group
        int msk = 1 << i;
        float om = __shfl_xor(m, msk);
        float os = __shfl_xor(s, msk);
        float nm = fmaxf(m, om);
        s = s * __expf(m - nm) + os * __expf(om - nm);
        m = nm;
    }
    float rn = 1.f / (s + 1e-16f);
    nr = 0;
    for (int p0 = start; p0 < end; p0 += 16, ++nr) {
        int p = p0 + l16;
        if (p < end) {
            float a = (nr < 4) ? av[nr] : as2[edge_src[p]];
            w2[p] = __float2half(__expf(lrelu(a + adn) - m) * rn);
        }
    }
}

// ---------------------------------------------------------------- aggregate layer 1 (R12/R15-proven form)
__global__ __launch_bounds__(256) void agg1_k(const __half* __restrict__ h1,
                                              const __half* __restrict__ w4,
                                              const int* __restrict__ edge_src,
                                              const int* __restrict__ offs,
                                              const int* __restrict__ counts,
                                              const float* __restrict__ b1,
                                              __half* __restrict__ out1, int N) {
    int lane = threadIdx.x & 63;
    int n = blockIdx.x * 4 + (threadIdx.x >> 6);
    if (n >= N) return;
    int start = offs[n];
    int end = start + counts[n];
    float acc0 = 0.f, acc1 = 0.f, acc2 = 0.f, acc3 = 0.f;
    int p = start;
    for (; p + 7 < end; p += 8) {
        int s[8]; uint2 hw[8], ww[8];
#pragma unroll
        for (int i = 0; i < 8; ++i) s[i] = edge_src[p + i];
#pragma unroll
        for (int i = 0; i < 8; ++i) ww[i] = *(const uint2*)(w4 + (size_t)(p + i) * 4);
#pragma unroll
        for (int i = 0; i < 8; ++i) hw[i] = *(const uint2*)(h1 + (size_t)s[i] * 256 + lane * 4);
#pragma unroll
        for (int i = 0; i < 8; ++i) {
            union { uint2 u; __half h[4]; } U, W;
            U.u = hw[i]; W.u = ww[i];
            acc0 += __half2float(U.h[0]) * __half2float(W.h[0]);
            acc1 += __half2float(U.h[1]) * __half2float(W.h[1]);
            acc2 += __half2float(U.h[2]) * __half2float(W.h[2]);
            acc3 += __half2float(U.h[3]) * __half2float(W.h[3]);
        }
    }
    for (; p < end; ++p) {
        int s0 = edge_src[p];
        union { uint2 u; __half h[4]; } U0, W0;
        W0.u = *(const uint2*)(w4 + (size_t)p * 4);
        U0.u = *(const uint2*)(h1 + (size_t)s0 * 256 + lane * 4);
        acc0 += __half2float(U0.h[0]) * __half2float(W0.h[0]);
        acc1 += __half2float(U0.h[1]) * __half2float(W0.h[1]);
        acc2 += __half2float(U0.h[2]) * __half2float(W0.h[2]);
        acc3 += __half2float(U0.h[3]) * __half2float(W0.h[3]);
    }
    union { uint2 u; __half h[4]; } O;
    O.h[0] = __float2half(fmaxf(acc0 + b1[lane], 0.f));
    O.h[1] = __float2half(fmaxf(acc1 + b1[64 + lane], 0.f));
    O.h[2] = __float2half(fmaxf(acc2 + b1[128 + lane], 0.f));
    O.h[3] = __float2half(fmaxf(acc3 + b1[192 + lane], 0.f));
    *(uint2*)(out1 + (size_t)n * 256 + lane * 4) = O.u;
}

// ---------------------------------------------------------------- aggregate layer 2 (R19-proven form)
__global__ __launch_bounds__(256) void agg2_k(const __half* __restrict__ h2,
                                              const __half* __restrict__ w2,
                                              const int* __restrict__ edge_src,
                                              const int* __restrict__ offs,
                                              const int* __restrict__ counts,
                                              const float* __restrict__ b2,
                                              __half* __restrict__ out2, int N) {
    int t = threadIdx.x;
    int l16 = t & 15;
    int n = blockIdx.x * 16 + (t >> 4);
    if (n >= N) return;
    int start = offs[n];
    int end = start + counts[n];
    float a0 = 0.f, a1 = 0.f, a2 = 0.f, a3 = 0.f;
    int p = start;
    for (; p + 7 < end; p += 8) {
        int s[8]; __half wv8[8]; uint2 hv8[8];
#pragma unroll
        for (int i = 0; i < 8; ++i) s[i] = edge_src[p + i];
#pragma unroll
        for (int i = 0; i < 8; ++i) wv8[i] = w2[p + i];
#pragma unroll
        for (int i = 0; i < 8; ++i)
            hv8[i] = *(const uint2*)(h2 + (size_t)s[i] * 64 + l16 * 4);
#pragma unroll
        for (int i = 0; i < 8; ++i) {
            union { uint2 u; __half h[4]; } U;
            U.u = hv8[i];
            float w = __half2float(wv8[i]);
            a0 += __half2float(U.h[0]) * w;
            a1 += __half2float(U.h[1]) * w;
            a2 += __half2float(U.h[2]) * w;
            a3 += __half2float(U.h[3]) * w;
        }
    }
    for (; p < end; ++p) {
        int s0 = edge_src[p];
        union { uint2 u; __half h[4]; } U;
        U.u = *(const uint2*)(h2 + (size_t)s0 * 64 + l16 * 4);
        float w = __half2float(w2[p]);
        a0 += __half2float(U.h[0]) * w;
        a1 += __half2float(U.h[1]) * w;
        a2 += __half2float(U.h[2]) * w;
        a3 += __half2float(U.h[3]) * w;
    }
    union { uint2 u; __half h[4]; } O;
    O.h[0] = __float2half(fmaxf(a0 + b2[l16 * 4],     0.f));
    O.h[1] = __float2half(fmaxf(a1 + b2[l16 * 4 + 1], 0.f));
    O.h[2] = __float2half(fmaxf(a2 + b2[l16 * 4 + 2], 0.f));
    O.h[3] = __float2half(fmaxf(a3 + b2[l16 * 4 + 3], 0.f));
    *(uint2*)(out2 + (size_t)n * 64 + l16 * 4) = O.u;
}

// ---------------------------------------------------------------- classifier head (fp16 input)
__global__ __launch_bounds__(256) void cls_k(const __half* __restrict__ hin,
                                             const float* __restrict__ Wc1,
                                             const float* __restrict__ bc1,
                                             const float* __restrict__ Wc2,
                                             const float* __restrict__ bc2,
                                             float* __restrict__ out, int N) {
    __shared__ float W1s[64 * 32];
    __shared__ float W2s[64];
    __shared__ float b1s[32];
    __shared__ float b2s[2];
    __shared__ float z[8][33];
    int t = threadIdx.x;
    for (int i = t; i < 2048; i += 256) W1s[i] = Wc1[i];
    if (t < 64) W2s[t] = Wc2[t];
    if (t < 32) b1s[t] = bc1[t];
    if (t < 2)  b2s[t] = bc2[t];
    __syncthreads();
    int nl = t >> 5, j = t & 31;
    int n = blockIdx.x * 8 + nl;
    float acc = b1s[j];
    if (n < N) {
        const __half* hr = hin + (size_t)n * 64;
#pragma unroll 8
        for (int l = 0; l < 64; ++l) acc += __half2float(hr[l]) * W1s[l * 32 + j];
    }
    z[nl][j] = fmaxf(acc, 0.f);
    __syncthreads();
    if (j < 2 && n < N) {
        float o = b2s[j];
#pragma unroll
        for (int q = 0; q < 32; ++q) o += z[nl][q] * W2s[q * 2 + j];
        out[(size_t)n * 2 + j] = o;
    }
}

// ---------------------------------------------------------------- launch
extern "C" void kernel_launch(void* const* d_in, const int* in_sizes, int n_in,
                              void* d_out, int out_size, void* d_ws, size_t ws_size,
                              hipStream_t stream) {
    const float* x      = (const float*)d_in[0];
    const int*   ei     = (const int*)d_in[1];
    const float* W1     = (const float*)d_in[2];
    const float* a_src1 = (const float*)d_in[3];
    const float* a_dst1 = (const float*)d_in[4];
    const float* b1     = (const float*)d_in[5];
    const float* W2     = (const float*)d_in[6];
    const float* a_src2 = (const float*)d_in[7];
    const float* a_dst2 = (const float*)d_in[8];
    const float* b2     = (const float*)d_in[9];
    const float* Wc1    = (const float*)d_in[10];
    const float* bc1    = (const float*)d_in[11];
    const float* Wc2    = (const float*)d_in[12];
    const float* bc2    = (const float*)d_in[13];

    char* ws = (char*)d_ws;
    size_t off = 0;
    auto alloc = [&](size_t bytes) -> void* {
        void* p = ws + off;
        off += (bytes + 255) & ~(size_t)255;
        return p;
    };
    int*       counts   = (int*)alloc((size_t)N_NODES * 4);   // contiguous with cursor
    int*       cursor   = (int*)alloc((size_t)N_NODES * 4);
    int*       offs     = (int*)alloc((size_t)N_NODES * 4);
    int*       chunks   = (int*)alloc(256);
    int*       edge_src = (int*)alloc((size_t)E_TOT * 4);
    float*     as1      = (float*)alloc((size_t)N_NODES * 16);
    float*     ad1      = (float*)alloc((size_t)N_NODES * 16);
    float*     as2      = (float*)alloc((size_t)N_NODES * 4);
    float*     ad2      = (float*)alloc((size_t)N_NODES * 4);
    __half*    w4       = (__half*)alloc((size_t)E_TOT * 8);        // fp16 L1 w; reused as L2 w
    _Float16*  Bt1      = (_Float16*)alloc((size_t)256 * 128 * 2);  // prepped W1
    _Float16*  Bt2      = (_Float16*)alloc((size_t)64 * 256 * 2);   // prepped W2
    __half*    h1h      = (__half*)alloc((size_t)N_NODES * 256 * 2);  // interleaved; reused as h2
    __half*    out1h    = (__half*)alloc((size_t)N_NODES * 256 * 2);  // interleaved
    __half*    out2h    = (__half*)alloc((size_t)N_NODES * 64 * 2);   // fp16 (cls input)
    __half*    h2h  = h1h;       // h1 dead after agg1
    __half*    w2b  = w4;        // w4 dead after agg1

    const int EB = (E_TOT + 255) / 256;
    const int NB4 = (N_NODES + 3) / 4;
    const int NB16 = (N_NODES + 15) / 16;     // 3125
    const int NCH = (N_NODES + 1023) / 1024;  // 49
    const int MB = (N_NODES + 63) / 64;       // 782

    // counts and cursor are adjacent 256-aligned allocs: one memset covers both
    hipMemsetAsync(counts, 0, (char*)cursor - (char*)counts + (size_t)N_NODES * 4, stream);

    prepcnt_k<<<48 + EB, 256, 0, stream>>>(W1, W2, Bt1, Bt2, ei, counts);
    scanA<<<NCH, 1024, 0, stream>>>(counts, offs, chunks, N_NODES);
    scanC<<<NCH, 1024, 0, stream>>>(offs, chunks, N_NODES, NCH);
    scatter_k<<<EB, 256, 0, stream>>>(ei, offs, cursor, edge_src);

    gemm_mfma<128, 256, 4, float, 1, 1><<<MB, 256, 0, stream>>>(
        x, Bt1, (_Float16*)h1h, a_src1, a_dst1, as1, ad1, N_NODES);
    stats1w_k<<<NB16, 256, 0, stream>>>(edge_src, as1, ad1, offs, counts, w4, N_NODES);
    agg1_k<<<NB4, 256, 0, stream>>>(h1h, w4, edge_src, offs, counts, b1, out1h, N_NODES);

    gemm_mfma<256, 64, 1, _Float16, 0, 2><<<MB, 256, 0, stream>>>(
        (const _Float16*)out1h, Bt2, (_Float16*)h2h, a_src2, a_dst2, as2, ad2, N_NODES);
    stats2w_k<<<NB16, 256, 0, stream>>>(edge_src, as2, ad2, offs, counts, w2b, N_NODES);
    agg2_k<<<NB16, 256, 0, stream>>>(h2h, w2b, edge_src, offs, counts, b2, out2h, N_NODES);

    cls_k<<<N_NODES / 8, 256, 0, stream>>>(out2h, Wc1, bc1, Wc2, bc2, (float*)d_out, N_NODES);
}